// Round 5
// baseline (912.882 us; speedup 1.0000x reference)
//
#include <hip/hip_runtime.h>
#include <hip/hip_bf16.h>

#define N_NODES 50000
#define DIM 128
#define N_GRAPHS 64
#define E_RAW 800000
#define E_TOT 850000
#define E_CAP 1200000   // >= E_TOT + 3*N_NODES (pad-to-4) with slack
#define NEG_SLOPE 0.2f

typedef unsigned int uint;

// round-to-nearest-even f32 -> bf16 (as uint16 in low bits)
__device__ __forceinline__ uint bf16r(float f) {
    uint u = __float_as_uint(f);
    return (u + 0x7fffu + ((u >> 16) & 1u)) >> 16;
}
__device__ __forceinline__ float bflo(uint h) { return __uint_as_float(h << 16); }
__device__ __forceinline__ float bfhi(uint h) { return __uint_as_float(h & 0xffff0000u); }

// ---------- init ----------
__global__ void init_kernel(int* deg, int* fillc, float* pooled, int* csr_src) {
    int i = blockIdx.x * blockDim.x + threadIdx.x;
    if (i < N_NODES) { deg[i] = 0; fillc[i] = 0; }
    if (i < N_GRAPHS * DIM) pooled[i] = 0.f;
    if (i < E_CAP) csr_src[i] = -1;
}

// ---------- CSR build (dst-sorted, segments padded to multiple of 4) ----------
__global__ void count_kernel(const int* __restrict__ ei, int* __restrict__ deg) {
    int e = blockIdx.x * blockDim.x + threadIdx.x;
    if (e >= E_TOT) return;
    int dst = (e < E_RAW) ? ei[E_RAW + e] : (e - E_RAW);
    atomicAdd(&deg[dst], 1);
}

__global__ void scan1_kernel(const int* __restrict__ deg, int* __restrict__ excl,
                             int* __restrict__ blksum, int n) {
    __shared__ int lds[256];
    int t = threadIdx.x;
    int i = blockIdx.x * 256 + t;
    int v = (i < n) ? ((deg[i] + 3) & ~3) : 0;   // pad degree to multiple of 4
    lds[t] = v;
    __syncthreads();
    int incl = v;
    for (int off = 1; off < 256; off <<= 1) {
        int y = (t >= off) ? lds[t - off] : 0;
        __syncthreads();
        incl += y;
        lds[t] = incl;
        __syncthreads();
    }
    if (i < n) excl[i] = incl - v;
    if (t == 255) blksum[blockIdx.x] = incl;
}

__global__ void scan2_kernel(int* __restrict__ blksum, int* __restrict__ row_ptr, int nblk) {
    __shared__ int lds[256];
    int t = threadIdx.x;
    int v = (t < nblk) ? blksum[t] : 0;
    lds[t] = v;
    __syncthreads();
    int incl = v;
    for (int off = 1; off < 256; off <<= 1) {
        int y = (t >= off) ? lds[t - off] : 0;
        __syncthreads();
        incl += y;
        lds[t] = incl;
        __syncthreads();
    }
    if (t < nblk) blksum[t] = incl - v;
    if (t == nblk - 1) row_ptr[N_NODES] = incl;
}

__global__ void scan3_kernel(int* __restrict__ row_ptr, const int* __restrict__ blksum, int n) {
    int i = blockIdx.x * blockDim.x + threadIdx.x;
    if (i < n) row_ptr[i] += blksum[i >> 8];
}

__global__ void fill_kernel(const int* __restrict__ ei, const int* __restrict__ row_ptr,
                            int* __restrict__ fillc, int* __restrict__ csr_src) {
    int e = blockIdx.x * blockDim.x + threadIdx.x;
    if (e >= E_TOT) return;
    int src, dst;
    if (e < E_RAW) { src = ei[e]; dst = ei[E_RAW + e]; }
    else           { src = dst = e - E_RAW; }
    int slot = row_ptr[dst] + atomicAdd(&fillc[dst], 1);
    csr_src[slot] = src;
}

// ---------- GEMM + fused attention dots; H written as packed bf16 ----------
__global__ __launch_bounds__(256) void gemm_dots_kernel(
    const float* __restrict__ X, const float* __restrict__ W,
    const float* __restrict__ asrc, const float* __restrict__ adst,
    uint* __restrict__ Hb, float* __restrict__ s1, float* __restrict__ s2, int nrows) {
    __shared__ float Wl[DIM][DIM];
    int t = threadIdx.x;
    for (int i = t; i < DIM * DIM / 4; i += 256)
        ((float4*)&Wl[0][0])[i] = ((const float4*)W)[i];
    __syncthreads();

    int tx = t & 15, ty = t >> 4;
    int row0 = blockIdx.x * 128 + ty * 8;
    int col0 = tx * 8;
    float acc[8][8];
#pragma unroll
    for (int r = 0; r < 8; ++r)
#pragma unroll
        for (int c = 0; c < 8; ++c) acc[r][c] = 0.f;

    for (int k = 0; k < DIM; k += 4) {
        float4 xr[8];
#pragma unroll
        for (int r = 0; r < 8; ++r) {
            int row = row0 + r;
            xr[r] = (row < nrows) ? *(const float4*)&X[row * DIM + k]
                                  : make_float4(0.f, 0.f, 0.f, 0.f);
        }
#pragma unroll
        for (int kk = 0; kk < 4; ++kk) {
            float w0[8];
#pragma unroll
            for (int c = 0; c < 8; ++c) w0[c] = Wl[k + kk][col0 + c];
#pragma unroll
            for (int r = 0; r < 8; ++r) {
                float xv = (kk == 0) ? xr[r].x : (kk == 1) ? xr[r].y : (kk == 2) ? xr[r].z : xr[r].w;
#pragma unroll
                for (int c = 0; c < 8; ++c) acc[r][c] = fmaf(xv, w0[c], acc[r][c]);
            }
        }
    }

    float a1r[8], a2r[8];
#pragma unroll
    for (int c = 0; c < 8; ++c) { a1r[c] = asrc[col0 + c]; a2r[c] = adst[col0 + c]; }

#pragma unroll
    for (int r = 0; r < 8; ++r) {
        int row = row0 + r;
        if (row < nrows) {
            uint us0 = bf16r(acc[r][0]) | (bf16r(acc[r][1]) << 16);
            uint us1 = bf16r(acc[r][2]) | (bf16r(acc[r][3]) << 16);
            uint us2 = bf16r(acc[r][4]) | (bf16r(acc[r][5]) << 16);
            uint us3 = bf16r(acc[r][6]) | (bf16r(acc[r][7]) << 16);
            *(uint4*)&Hb[(size_t)row * 64 + (col0 >> 1)] = make_uint4(us0, us1, us2, us3);
        }
        float p1 = 0.f, p2 = 0.f;
#pragma unroll
        for (int c = 0; c < 8; ++c) { p1 = fmaf(acc[r][c], a1r[c], p1); p2 = fmaf(acc[r][c], a2r[c], p2); }
#pragma unroll
        for (int m = 1; m < 16; m <<= 1) { p1 += __shfl_xor(p1, m); p2 += __shfl_xor(p2, m); }
        if (tx == 0 && row < nrows) { s1[row] = p1; s2[row] = p2; }
    }
}

// ---------- fused softmax + aggregation ----------
// One wave per dst node. Lanes split into 4 groups of 16 (grp = lane>>4,
// sub = lane&15). Group g handles edges beg+4t+g; each lane loads uint4 so a
// group covers one 256 B bf16 row -> ONE dwordx4 instruction fetches 4 rows.
// Each group keeps private acc[8] (dims sub*8..sub*8+7) and wsum; final
// __shfl_xor(16/32) merges groups. Two quads per iteration (8 edges in flight).
__global__ __launch_bounds__(256) void agg_kernel(
    const uint4* __restrict__ Hb4, const int* __restrict__ csr_src,
    const int* __restrict__ row_ptr, const float* __restrict__ s1,
    const float* __restrict__ s2n, const float* __restrict__ bias,
    float* __restrict__ Xout, const int* __restrict__ batch,
    float* __restrict__ pooled, int pool_flag, int n) {
    int wid = (blockIdx.x * blockDim.x + threadIdx.x) >> 6;
    int lane = threadIdx.x & 63;
    if (wid >= n) return;
    int grp = lane >> 4;
    int sub = lane & 15;
    int beg = row_ptr[wid], end = row_ptr[wid + 1];
    float s2v = s2n[wid];

    float acc[8];
#pragma unroll
    for (int k = 0; k < 8; ++k) acc[k] = 0.f;
    float wsum = 0.f;

    for (int s = beg; s < end; s += 8) {
        // quad A (always valid: segments are padded to multiple of 4)
        int snA = csr_src[s + grp];
        int rA = (snA < 0) ? 0 : snA;
        // quad B (maybe fully absent)
        int idxB = s + 4 + grp;
        bool vB = idxB < end;
        int snB = vB ? csr_src[idxB] : -1;
        int rB = (snB < 0) ? 0 : snB;

        uint4 hA = Hb4[(size_t)rA * 16 + sub];
        uint4 hB = Hb4[(size_t)rB * 16 + sub];
        float s1A = s1[rA];
        float s1B = s1[rB];

        float alA = s1A + s2v; alA = (alA > 0.f) ? alA : NEG_SLOPE * alA;
        float alB = s1B + s2v; alB = (alB > 0.f) ? alB : NEG_SLOPE * alB;
        float wA = (snA < 0) ? 0.f : __expf(alA);
        float wB = (snB < 0) ? 0.f : __expf(alB);
        wsum += wA + wB;

        acc[0] = fmaf(wA, bflo(hA.x), acc[0]); acc[1] = fmaf(wA, bfhi(hA.x), acc[1]);
        acc[2] = fmaf(wA, bflo(hA.y), acc[2]); acc[3] = fmaf(wA, bfhi(hA.y), acc[3]);
        acc[4] = fmaf(wA, bflo(hA.z), acc[4]); acc[5] = fmaf(wA, bfhi(hA.z), acc[5]);
        acc[6] = fmaf(wA, bflo(hA.w), acc[6]); acc[7] = fmaf(wA, bfhi(hA.w), acc[7]);

        acc[0] = fmaf(wB, bflo(hB.x), acc[0]); acc[1] = fmaf(wB, bfhi(hB.x), acc[1]);
        acc[2] = fmaf(wB, bflo(hB.y), acc[2]); acc[3] = fmaf(wB, bfhi(hB.y), acc[3]);
        acc[4] = fmaf(wB, bflo(hB.z), acc[4]); acc[5] = fmaf(wB, bfhi(hB.z), acc[5]);
        acc[6] = fmaf(wB, bflo(hB.w), acc[6]); acc[7] = fmaf(wB, bfhi(hB.w), acc[7]);
    }

    // merge the 4 groups (lanes with equal sub hold the same dim slice)
#pragma unroll
    for (int m = 16; m < 64; m <<= 1) {
#pragma unroll
        for (int k = 0; k < 8; ++k) acc[k] += __shfl_xor(acc[k], m);
        wsum += __shfl_xor(wsum, m);
    }

    if (grp == 0) {
        float inv = 1.f / (wsum + 1e-16f);
        float4 b0 = ((const float4*)bias)[sub * 2];
        float4 b1 = ((const float4*)bias)[sub * 2 + 1];
        float o[8];
        o[0] = fmaxf(fmaf(acc[0], inv, b0.x), 0.f);
        o[1] = fmaxf(fmaf(acc[1], inv, b0.y), 0.f);
        o[2] = fmaxf(fmaf(acc[2], inv, b0.z), 0.f);
        o[3] = fmaxf(fmaf(acc[3], inv, b0.w), 0.f);
        o[4] = fmaxf(fmaf(acc[4], inv, b1.x), 0.f);
        o[5] = fmaxf(fmaf(acc[5], inv, b1.y), 0.f);
        o[6] = fmaxf(fmaf(acc[6], inv, b1.z), 0.f);
        o[7] = fmaxf(fmaf(acc[7], inv, b1.w), 0.f);
        *(float4*)&Xout[(size_t)wid * DIM + sub * 8]     = make_float4(o[0], o[1], o[2], o[3]);
        *(float4*)&Xout[(size_t)wid * DIM + sub * 8 + 4] = make_float4(o[4], o[5], o[6], o[7]);
        if (pool_flag) {
            int g = batch[wid];
#pragma unroll
            for (int k = 0; k < 8; ++k) atomicAdd(&pooled[g * DIM + sub * 8 + k], o[k]);
        }
    }
}

__global__ void final_kernel(const float* __restrict__ pooled, const float* __restrict__ Wf,
                             const float* __restrict__ bf, float* __restrict__ y) {
    int wid = (blockIdx.x * blockDim.x + threadIdx.x) >> 6;
    int lane = threadIdx.x & 63;
    if (wid >= N_GRAPHS) return;
    float2 p = *(const float2*)&pooled[wid * DIM + 2 * lane];
    float2 w = *(const float2*)&Wf[2 * lane];
    float v = p.x * w.x + p.y * w.y;
    for (int off = 32; off; off >>= 1) v += __shfl_down(v, off);
    if (lane == 0) y[wid] = v + bf[0];
}

extern "C" void kernel_launch(void* const* d_in, const int* in_sizes, int n_in,
                              void* d_out, int out_size, void* d_ws, size_t ws_size,
                              hipStream_t stream) {
    const float* x       = (const float*)d_in[0];
    const int*   ei      = (const int*)d_in[1];
    const int*   batch   = (const int*)d_in[2];
    const float* Ws      = (const float*)d_in[3];
    const float* att_src = (const float*)d_in[4];
    const float* att_dst = (const float*)d_in[5];
    const float* biases  = (const float*)d_in[6];
    const float* Wf      = (const float*)d_in[7];
    const float* bf      = (const float*)d_in[8];
    float* y = (float*)d_out;

    char* p = (char*)d_ws;
    auto alloc = [&](size_t bytes) -> void* {
        void* r = (void*)p;
        p += (bytes + 255) & ~(size_t)255;
        return r;
    };
    float* xA      = (float*)alloc((size_t)N_NODES * DIM * 4);
    float* xB      = (float*)alloc((size_t)N_NODES * DIM * 4);
    uint*  Hb      = (uint*)alloc((size_t)N_NODES * 64 * 4);   // bf16x2 packed
    int*   csr_src = (int*)alloc((size_t)E_CAP * 4);
    int*   deg     = (int*)alloc((size_t)N_NODES * 4);
    int*   fillc   = (int*)alloc((size_t)N_NODES * 4);
    int*   row_ptr = (int*)alloc((size_t)(N_NODES + 1) * 4);
    int*   blksum  = (int*)alloc(256 * 4);
    float* s1      = (float*)alloc((size_t)N_NODES * 4);
    float* s2      = (float*)alloc((size_t)N_NODES * 4);
    float* pooled  = (float*)alloc((size_t)N_GRAPHS * DIM * 4);

    const int BN = 256;
    const int gN   = (N_NODES + BN - 1) / BN;
    const int gE   = (E_TOT + BN - 1) / BN;
    const int gI   = (E_CAP + BN - 1) / BN;
    const int gNW  = (N_NODES * 64 + BN - 1) / BN;  // one wave per node
    const int nblk = gN;

    init_kernel<<<gI, BN, 0, stream>>>(deg, fillc, pooled, csr_src);
    count_kernel<<<gE, BN, 0, stream>>>(ei, deg);
    scan1_kernel<<<nblk, BN, 0, stream>>>(deg, row_ptr, blksum, N_NODES);
    scan2_kernel<<<1, BN, 0, stream>>>(blksum, row_ptr, nblk);
    scan3_kernel<<<gN, BN, 0, stream>>>(row_ptr, blksum, N_NODES);
    fill_kernel<<<gE, BN, 0, stream>>>(ei, row_ptr, fillc, csr_src);

    const float* xin = x;
    float* xout = xA;
    for (int l = 0; l < 3; ++l) {
        const float* W  = Ws + (size_t)l * DIM * DIM;
        const float* as = att_src + (size_t)l * DIM;
        const float* ad = att_dst + (size_t)l * DIM;
        const float* b  = biases + (size_t)l * DIM;

        gemm_dots_kernel<<<(N_NODES + 127) / 128, BN, 0, stream>>>(xin, W, as, ad, Hb, s1, s2, N_NODES);
        agg_kernel<<<gNW, BN, 0, stream>>>((const uint4*)Hb, csr_src, row_ptr, s1, s2, b,
                                           xout, batch, pooled,
                                           (l == 2) ? 1 : 0, N_NODES);
        xin = xout;
        xout = (l == 0) ? xB : xA;
    }

    final_kernel<<<(N_GRAPHS * 64 + BN - 1) / BN, BN, 0, stream>>>(pooled, Wf, bf, y);
    (void)ws_size; (void)n_in; (void)in_sizes; (void)out_size;
}

// Round 6
// 605.504 us; speedup vs baseline: 1.5076x; 1.5076x over previous
//
#include <hip/hip_runtime.h>
#include <hip/hip_bf16.h>

#define N_NODES 50000
#define DIM 128
#define N_GRAPHS 64
#define E_RAW 800000
#define E_TOT 850000
#define E_CAP 1200000   // >= E_TOT + 7*N_NODES (pad-to-8)
#define NEG_SLOPE 0.2f

typedef unsigned int uint;

// round-to-nearest-even f32 -> bf16 (as uint16 in low bits)
__device__ __forceinline__ uint bf16r(float f) {
    uint u = __float_as_uint(f);
    return (u + 0x7fffu + ((u >> 16) & 1u)) >> 16;
}

// ---------- init ----------
__global__ void init_kernel(int* deg, int* fillc, float* pooled, int* csr_src) {
    int i = blockIdx.x * blockDim.x + threadIdx.x;
    if (i < N_NODES) { deg[i] = 0; fillc[i] = 0; }
    if (i < N_GRAPHS * DIM) pooled[i] = 0.f;
    if (i < E_CAP) csr_src[i] = -1;
}

// ---------- CSR build (dst-sorted, segments padded to multiple of 8) ----------
__global__ void count_kernel(const int* __restrict__ ei, int* __restrict__ deg) {
    int e = blockIdx.x * blockDim.x + threadIdx.x;
    if (e >= E_TOT) return;
    int dst = (e < E_RAW) ? ei[E_RAW + e] : (e - E_RAW);
    atomicAdd(&deg[dst], 1);
}

__global__ void scan1_kernel(const int* __restrict__ deg, int* __restrict__ excl,
                             int* __restrict__ blksum, int n) {
    __shared__ int lds[256];
    int t = threadIdx.x;
    int i = blockIdx.x * 256 + t;
    int v = (i < n) ? ((deg[i] + 7) & ~7) : 0;   // pad degree to multiple of 8
    lds[t] = v;
    __syncthreads();
    int incl = v;
    for (int off = 1; off < 256; off <<= 1) {
        int y = (t >= off) ? lds[t - off] : 0;
        __syncthreads();
        incl += y;
        lds[t] = incl;
        __syncthreads();
    }
    if (i < n) excl[i] = incl - v;
    if (t == 255) blksum[blockIdx.x] = incl;
}

__global__ void scan2_kernel(int* __restrict__ blksum, int* __restrict__ row_ptr, int nblk) {
    __shared__ int lds[256];
    int t = threadIdx.x;
    int v = (t < nblk) ? blksum[t] : 0;
    lds[t] = v;
    __syncthreads();
    int incl = v;
    for (int off = 1; off < 256; off <<= 1) {
        int y = (t >= off) ? lds[t - off] : 0;
        __syncthreads();
        incl += y;
        lds[t] = incl;
        __syncthreads();
    }
    if (t < nblk) blksum[t] = incl - v;
    if (t == nblk - 1) row_ptr[N_NODES] = incl;
}

__global__ void scan3_kernel(int* __restrict__ row_ptr, const int* __restrict__ blksum, int n) {
    int i = blockIdx.x * blockDim.x + threadIdx.x;
    if (i < n) row_ptr[i] += blksum[i >> 8];
}

__global__ void fill_kernel(const int* __restrict__ ei, const int* __restrict__ row_ptr,
                            int* __restrict__ fillc, int* __restrict__ csr_src) {
    int e = blockIdx.x * blockDim.x + threadIdx.x;
    if (e >= E_TOT) return;
    int src, dst;
    if (e < E_RAW) { src = ei[e]; dst = ei[E_RAW + e]; }
    else           { src = dst = e - E_RAW; }
    int slot = row_ptr[dst] + atomicAdd(&fillc[dst], 1);
    csr_src[slot] = src;
}

// ---------- per-segment src-sort: one wave per node, 64-lane bitonic ----------
// Sorting each dst's edge list by src makes concurrently-running agg waves walk
// ascending src windows in loose lockstep -> gathers hit a small hot slice of Hb
// that every XCD L2 can hold. Pads (-1) sort to the front; harmless (w=0).
__global__ __launch_bounds__(256) void sort_kernel(int* __restrict__ csr_src,
                                                   const int* __restrict__ row_ptr, int n) {
    int wid = (blockIdx.x * blockDim.x + threadIdx.x) >> 6;
    int lane = threadIdx.x & 63;
    if (wid >= n) return;
    int beg = row_ptr[wid], end = row_ptr[wid + 1];
    int len = end - beg;
    if (len > 64) return;  // vanishingly rare for Poisson(17); skip (locality only)
    int v = (lane < len) ? csr_src[beg + lane] : 0x7fffffff;
#pragma unroll
    for (int k = 2; k <= 64; k <<= 1) {
        for (int j = k >> 1; j >= 1; j >>= 1) {
            int other = __shfl_xor(v, j);
            bool up = ((lane & k) == 0);
            bool lower = ((lane & j) == 0);
            int mn = min(v, other), mx = max(v, other);
            v = (lower == up) ? mn : mx;
        }
    }
    if (lane < len) csr_src[beg + lane] = v;
}

// ---------- GEMM + fused attention dots; H written as packed bf16 ----------
__global__ __launch_bounds__(256) void gemm_dots_kernel(
    const float* __restrict__ X, const float* __restrict__ W,
    const float* __restrict__ asrc, const float* __restrict__ adst,
    uint* __restrict__ Hb, float* __restrict__ s1, float* __restrict__ s2, int nrows) {
    __shared__ float Wl[DIM][DIM];
    int t = threadIdx.x;
    for (int i = t; i < DIM * DIM / 4; i += 256)
        ((float4*)&Wl[0][0])[i] = ((const float4*)W)[i];
    __syncthreads();

    int tx = t & 15, ty = t >> 4;
    int row0 = blockIdx.x * 128 + ty * 8;
    int col0 = tx * 8;
    float acc[8][8];
#pragma unroll
    for (int r = 0; r < 8; ++r)
#pragma unroll
        for (int c = 0; c < 8; ++c) acc[r][c] = 0.f;

    for (int k = 0; k < DIM; k += 4) {
        float4 xr[8];
#pragma unroll
        for (int r = 0; r < 8; ++r) {
            int row = row0 + r;
            xr[r] = (row < nrows) ? *(const float4*)&X[row * DIM + k]
                                  : make_float4(0.f, 0.f, 0.f, 0.f);
        }
#pragma unroll
        for (int kk = 0; kk < 4; ++kk) {
            float w0[8];
#pragma unroll
            for (int c = 0; c < 8; ++c) w0[c] = Wl[k + kk][col0 + c];
#pragma unroll
            for (int r = 0; r < 8; ++r) {
                float xv = (kk == 0) ? xr[r].x : (kk == 1) ? xr[r].y : (kk == 2) ? xr[r].z : xr[r].w;
#pragma unroll
                for (int c = 0; c < 8; ++c) acc[r][c] = fmaf(xv, w0[c], acc[r][c]);
            }
        }
    }

    float a1r[8], a2r[8];
#pragma unroll
    for (int c = 0; c < 8; ++c) { a1r[c] = asrc[col0 + c]; a2r[c] = adst[col0 + c]; }

#pragma unroll
    for (int r = 0; r < 8; ++r) {
        int row = row0 + r;
        if (row < nrows) {
            uint us0 = bf16r(acc[r][0]) | (bf16r(acc[r][1]) << 16);
            uint us1 = bf16r(acc[r][2]) | (bf16r(acc[r][3]) << 16);
            uint us2 = bf16r(acc[r][4]) | (bf16r(acc[r][5]) << 16);
            uint us3 = bf16r(acc[r][6]) | (bf16r(acc[r][7]) << 16);
            *(uint4*)&Hb[(size_t)row * 64 + (col0 >> 1)] = make_uint4(us0, us1, us2, us3);
        }
        float p1 = 0.f, p2 = 0.f;
#pragma unroll
        for (int c = 0; c < 8; ++c) { p1 = fmaf(acc[r][c], a1r[c], p1); p2 = fmaf(acc[r][c], a2r[c], p2); }
#pragma unroll
        for (int m = 1; m < 16; m <<= 1) { p1 += __shfl_xor(p1, m); p2 += __shfl_xor(p2, m); }
        if (tx == 0 && row < nrows) { s1[row] = p1; s2[row] = p2; }
    }
}

// ---------- fused softmax + aggregation: one wave per dst node (R4 structure) ----------
__global__ __launch_bounds__(256) void agg_kernel(
    const uint* __restrict__ Hb, const int* __restrict__ csr_src,
    const int* __restrict__ row_ptr, const float* __restrict__ s1,
    const float* __restrict__ s2n, const float* __restrict__ bias,
    float2* __restrict__ Xout2, const int* __restrict__ batch,
    float* __restrict__ pooled, int pool_flag, int n) {
    int wid = (blockIdx.x * blockDim.x + threadIdx.x) >> 6;
    int lane = threadIdx.x & 63;
    if (wid >= n) return;
    int beg = row_ptr[wid], end = row_ptr[wid + 1];
    float s2v = s2n[wid];
    float2 acc = make_float2(0.f, 0.f);
    float wsum = 0.f;

    for (int s = beg; s < end; s += 8) {
        int4 a = *(const int4*)&csr_src[s];
        int4 b = *(const int4*)&csr_src[s + 4];
        int sn[8] = {a.x, a.y, a.z, a.w, b.x, b.y, b.z, b.w};
        uint hv[8];
#pragma unroll
        for (int j = 0; j < 8; ++j) {
            int r = (sn[j] < 0) ? 0 : sn[j];
            hv[j] = Hb[(size_t)r * 64 + lane];
        }
        float w[8];
#pragma unroll
        for (int j = 0; j < 8; ++j) {
            int r = (sn[j] < 0) ? 0 : sn[j];
            float al = s1[r] + s2v;
            al = (al > 0.f) ? al : NEG_SLOPE * al;
            float e = __expf(al);
            w[j] = (sn[j] < 0) ? 0.f : e;
            wsum += w[j];
        }
#pragma unroll
        for (int j = 0; j < 8; ++j) {
            float lo = __uint_as_float(hv[j] << 16);
            float hi = __uint_as_float(hv[j] & 0xffff0000u);
            acc.x = fmaf(w[j], lo, acc.x);
            acc.y = fmaf(w[j], hi, acc.y);
        }
    }

    float inv = 1.f / (wsum + 1e-16f);
    float2 b2 = ((const float2*)bias)[lane];
    acc.x = fmaxf(fmaf(acc.x, inv, b2.x), 0.f);
    acc.y = fmaxf(fmaf(acc.y, inv, b2.y), 0.f);
    Xout2[(size_t)wid * 64 + lane] = acc;
    if (pool_flag) {
        int g = batch[wid];
        atomicAdd(&pooled[g * DIM + 2 * lane], acc.x);
        atomicAdd(&pooled[g * DIM + 2 * lane + 1], acc.y);
    }
}

__global__ void final_kernel(const float* __restrict__ pooled, const float* __restrict__ Wf,
                             const float* __restrict__ bf, float* __restrict__ y) {
    int wid = (blockIdx.x * blockDim.x + threadIdx.x) >> 6;
    int lane = threadIdx.x & 63;
    if (wid >= N_GRAPHS) return;
    float2 p = *(const float2*)&pooled[wid * DIM + 2 * lane];
    float2 w = *(const float2*)&Wf[2 * lane];
    float v = p.x * w.x + p.y * w.y;
    for (int off = 32; off; off >>= 1) v += __shfl_down(v, off);
    if (lane == 0) y[wid] = v + bf[0];
}

extern "C" void kernel_launch(void* const* d_in, const int* in_sizes, int n_in,
                              void* d_out, int out_size, void* d_ws, size_t ws_size,
                              hipStream_t stream) {
    const float* x       = (const float*)d_in[0];
    const int*   ei      = (const int*)d_in[1];
    const int*   batch   = (const int*)d_in[2];
    const float* Ws      = (const float*)d_in[3];
    const float* att_src = (const float*)d_in[4];
    const float* att_dst = (const float*)d_in[5];
    const float* biases  = (const float*)d_in[6];
    const float* Wf      = (const float*)d_in[7];
    const float* bf      = (const float*)d_in[8];
    float* y = (float*)d_out;

    char* p = (char*)d_ws;
    auto alloc = [&](size_t bytes) -> void* {
        void* r = (void*)p;
        p += (bytes + 255) & ~(size_t)255;
        return r;
    };
    float* xA      = (float*)alloc((size_t)N_NODES * DIM * 4);
    float* xB      = (float*)alloc((size_t)N_NODES * DIM * 4);
    uint*  Hb      = (uint*)alloc((size_t)N_NODES * 64 * 4);   // bf16x2 packed
    int*   csr_src = (int*)alloc((size_t)E_CAP * 4);
    int*   deg     = (int*)alloc((size_t)N_NODES * 4);
    int*   fillc   = (int*)alloc((size_t)N_NODES * 4);
    int*   row_ptr = (int*)alloc((size_t)(N_NODES + 1) * 4);
    int*   blksum  = (int*)alloc(256 * 4);
    float* s1      = (float*)alloc((size_t)N_NODES * 4);
    float* s2      = (float*)alloc((size_t)N_NODES * 4);
    float* pooled  = (float*)alloc((size_t)N_GRAPHS * DIM * 4);

    const int BN = 256;
    const int gN   = (N_NODES + BN - 1) / BN;
    const int gE   = (E_TOT + BN - 1) / BN;
    const int gI   = (E_CAP + BN - 1) / BN;
    const int gNW  = (N_NODES * 64 + BN - 1) / BN;  // one wave per node
    const int nblk = gN;

    init_kernel<<<gI, BN, 0, stream>>>(deg, fillc, pooled, csr_src);
    count_kernel<<<gE, BN, 0, stream>>>(ei, deg);
    scan1_kernel<<<nblk, BN, 0, stream>>>(deg, row_ptr, blksum, N_NODES);
    scan2_kernel<<<1, BN, 0, stream>>>(blksum, row_ptr, nblk);
    scan3_kernel<<<gN, BN, 0, stream>>>(row_ptr, blksum, N_NODES);
    fill_kernel<<<gE, BN, 0, stream>>>(ei, row_ptr, fillc, csr_src);
    sort_kernel<<<gNW, BN, 0, stream>>>(csr_src, row_ptr, N_NODES);

    const float* xin = x;
    float* xout = xA;
    for (int l = 0; l < 3; ++l) {
        const float* W  = Ws + (size_t)l * DIM * DIM;
        const float* as = att_src + (size_t)l * DIM;
        const float* ad = att_dst + (size_t)l * DIM;
        const float* b  = biases + (size_t)l * DIM;

        gemm_dots_kernel<<<(N_NODES + 127) / 128, BN, 0, stream>>>(xin, W, as, ad, Hb, s1, s2, N_NODES);
        agg_kernel<<<gNW, BN, 0, stream>>>(Hb, csr_src, row_ptr, s1, s2, b,
                                           (float2*)xout, batch, pooled,
                                           (l == 2) ? 1 : 0, N_NODES);
        xin = xout;
        xout = (l == 0) ? xB : xA;
    }

    final_kernel<<<(N_GRAPHS * 64 + BN - 1) / BN, BN, 0, stream>>>(pooled, Wf, bf, y);
    (void)ws_size; (void)n_in; (void)in_sizes; (void)out_size;
}

// Round 7
// 560.657 us; speedup vs baseline: 1.6282x; 1.0800x over previous
//
#include <hip/hip_runtime.h>
#include <hip/hip_bf16.h>

#define N_NODES 50000
#define DIM 128
#define N_GRAPHS 64
#define E_RAW 800000
#define E_TOT 850000
#define E_CAP 1200000   // >= E_TOT + 7*N_NODES (pad-to-8)
#define NEG_SLOPE 0.2f

typedef unsigned int uint;
typedef unsigned short ushort;
typedef float v2f __attribute__((ext_vector_type(2)));

// ---------- init ----------
__global__ void init_kernel(int* deg, int* fillc, float* pooled, int* csr_src) {
    int i = blockIdx.x * blockDim.x + threadIdx.x;
    if (i < N_NODES) { deg[i] = 0; fillc[i] = 0; }
    if (i < N_GRAPHS * DIM) pooled[i] = 0.f;
    if (i < E_CAP) csr_src[i] = -1;
}

// ---------- CSR build (dst-sorted, segments padded to multiple of 8) ----------
__global__ void count_kernel(const int* __restrict__ ei, int* __restrict__ deg) {
    int e = blockIdx.x * blockDim.x + threadIdx.x;
    if (e >= E_TOT) return;
    int dst = (e < E_RAW) ? ei[E_RAW + e] : (e - E_RAW);
    atomicAdd(&deg[dst], 1);
}

__global__ void scan1_kernel(const int* __restrict__ deg, int* __restrict__ excl,
                             int* __restrict__ blksum, int n) {
    __shared__ int lds[256];
    int t = threadIdx.x;
    int i = blockIdx.x * 256 + t;
    int v = (i < n) ? ((deg[i] + 7) & ~7) : 0;   // pad degree to multiple of 8
    lds[t] = v;
    __syncthreads();
    int incl = v;
    for (int off = 1; off < 256; off <<= 1) {
        int y = (t >= off) ? lds[t - off] : 0;
        __syncthreads();
        incl += y;
        lds[t] = incl;
        __syncthreads();
    }
    if (i < n) excl[i] = incl - v;
    if (t == 255) blksum[blockIdx.x] = incl;
}

__global__ void scan2_kernel(int* __restrict__ blksum, int* __restrict__ row_ptr, int nblk) {
    __shared__ int lds[256];
    int t = threadIdx.x;
    int v = (t < nblk) ? blksum[t] : 0;
    lds[t] = v;
    __syncthreads();
    int incl = v;
    for (int off = 1; off < 256; off <<= 1) {
        int y = (t >= off) ? lds[t - off] : 0;
        __syncthreads();
        incl += y;
        lds[t] = incl;
        __syncthreads();
    }
    if (t < nblk) blksum[t] = incl - v;
    if (t == nblk - 1) row_ptr[N_NODES] = incl;
}

__global__ void scan3_kernel(int* __restrict__ row_ptr, const int* __restrict__ blksum, int n) {
    int i = blockIdx.x * blockDim.x + threadIdx.x;
    if (i < n) row_ptr[i] += blksum[i >> 8];
}

__global__ void fill_kernel(const int* __restrict__ ei, const int* __restrict__ row_ptr,
                            int* __restrict__ fillc, int* __restrict__ csr_src) {
    int e = blockIdx.x * blockDim.x + threadIdx.x;
    if (e >= E_TOT) return;
    int src, dst;
    if (e < E_RAW) { src = ei[e]; dst = ei[E_RAW + e]; }
    else           { src = dst = e - E_RAW; }
    int slot = row_ptr[dst] + atomicAdd(&fillc[dst], 1);
    csr_src[slot] = src;
}

// ---------- GEMM + fused attention dots; H written as packed fp8 e4m3 ----------
// s1/s2 are computed from the fp32 accumulators, so softmax logits are exact;
// only the aggregated values carry fp8 quantization (~1% after degree-averaging).
__global__ __launch_bounds__(256) void gemm_dots_kernel(
    const float* __restrict__ X, const float* __restrict__ W,
    const float* __restrict__ asrc, const float* __restrict__ adst,
    uint* __restrict__ Hb, float* __restrict__ s1, float* __restrict__ s2, int nrows) {
    __shared__ float Wl[DIM][DIM];
    int t = threadIdx.x;
    for (int i = t; i < DIM * DIM / 4; i += 256)
        ((float4*)&Wl[0][0])[i] = ((const float4*)W)[i];
    __syncthreads();

    int tx = t & 15, ty = t >> 4;
    int row0 = blockIdx.x * 128 + ty * 8;
    int col0 = tx * 8;
    float acc[8][8];
#pragma unroll
    for (int r = 0; r < 8; ++r)
#pragma unroll
        for (int c = 0; c < 8; ++c) acc[r][c] = 0.f;

    for (int k = 0; k < DIM; k += 4) {
        float4 xr[8];
#pragma unroll
        for (int r = 0; r < 8; ++r) {
            int row = row0 + r;
            xr[r] = (row < nrows) ? *(const float4*)&X[row * DIM + k]
                                  : make_float4(0.f, 0.f, 0.f, 0.f);
        }
#pragma unroll
        for (int kk = 0; kk < 4; ++kk) {
            float w0[8];
#pragma unroll
            for (int c = 0; c < 8; ++c) w0[c] = Wl[k + kk][col0 + c];
#pragma unroll
            for (int r = 0; r < 8; ++r) {
                float xv = (kk == 0) ? xr[r].x : (kk == 1) ? xr[r].y : (kk == 2) ? xr[r].z : xr[r].w;
#pragma unroll
                for (int c = 0; c < 8; ++c) acc[r][c] = fmaf(xv, w0[c], acc[r][c]);
            }
        }
    }

    float a1r[8], a2r[8];
#pragma unroll
    for (int c = 0; c < 8; ++c) { a1r[c] = asrc[col0 + c]; a2r[c] = adst[col0 + c]; }

#pragma unroll
    for (int r = 0; r < 8; ++r) {
        int row = row0 + r;
        if (row < nrows) {
            // pack 8 fp32 -> 8 fp8 e4m3 (2 dwords), HW round
            int w0 = __builtin_amdgcn_cvt_pk_fp8_f32(acc[r][0], acc[r][1], 0, false);
            w0     = __builtin_amdgcn_cvt_pk_fp8_f32(acc[r][2], acc[r][3], w0, true);
            int w1 = __builtin_amdgcn_cvt_pk_fp8_f32(acc[r][4], acc[r][5], 0, false);
            w1     = __builtin_amdgcn_cvt_pk_fp8_f32(acc[r][6], acc[r][7], w1, true);
            *(uint2*)&Hb[(size_t)row * 32 + tx * 2] = make_uint2((uint)w0, (uint)w1);
        }
        float p1 = 0.f, p2 = 0.f;
#pragma unroll
        for (int c = 0; c < 8; ++c) { p1 = fmaf(acc[r][c], a1r[c], p1); p2 = fmaf(acc[r][c], a2r[c], p2); }
#pragma unroll
        for (int m = 1; m < 16; m <<= 1) { p1 += __shfl_xor(p1, m); p2 += __shfl_xor(p2, m); }
        if (tx == 0 && row < nrows) { s1[row] = p1; s2[row] = p2; }
    }
}

// ---------- fused softmax + aggregation: one wave per dst node ----------
// H rows are fp8 (128 B = 2 cache lines). Lane loads ushort = 2 fp8 = dims
// {2*lane, 2*lane+1}; HW v_cvt_pk_f32_fp8 unpacks to float2.
__global__ __launch_bounds__(256) void agg_kernel(
    const ushort* __restrict__ Hb16, const int* __restrict__ csr_src,
    const int* __restrict__ row_ptr, const float* __restrict__ s1,
    const float* __restrict__ s2n, const float* __restrict__ bias,
    float2* __restrict__ Xout2, const int* __restrict__ batch,
    float* __restrict__ pooled, int pool_flag, int n) {
    int wid = (blockIdx.x * blockDim.x + threadIdx.x) >> 6;
    int lane = threadIdx.x & 63;
    if (wid >= n) return;
    int beg = row_ptr[wid], end = row_ptr[wid + 1];
    float s2v = s2n[wid];
    float2 acc = make_float2(0.f, 0.f);
    float wsum = 0.f;

    for (int s = beg; s < end; s += 8) {
        int4 a = *(const int4*)&csr_src[s];
        int4 b = *(const int4*)&csr_src[s + 4];
        int sn[8] = {a.x, a.y, a.z, a.w, b.x, b.y, b.z, b.w};
        ushort hv[8];
#pragma unroll
        for (int j = 0; j < 8; ++j) {
            int r = (sn[j] < 0) ? 0 : sn[j];
            hv[j] = Hb16[(size_t)r * 64 + lane];
        }
        float w[8];
#pragma unroll
        for (int j = 0; j < 8; ++j) {
            int r = (sn[j] < 0) ? 0 : sn[j];
            float al = s1[r] + s2v;
            al = (al > 0.f) ? al : NEG_SLOPE * al;
            float e = __expf(al);
            w[j] = (sn[j] < 0) ? 0.f : e;
            wsum += w[j];
        }
#pragma unroll
        for (int j = 0; j < 8; ++j) {
            v2f f = __builtin_amdgcn_cvt_pk_f32_fp8((int)hv[j], false);
            acc.x = fmaf(w[j], f.x, acc.x);
            acc.y = fmaf(w[j], f.y, acc.y);
        }
    }

    float inv = 1.f / (wsum + 1e-16f);
    float2 b2 = ((const float2*)bias)[lane];
    acc.x = fmaxf(fmaf(acc.x, inv, b2.x), 0.f);
    acc.y = fmaxf(fmaf(acc.y, inv, b2.y), 0.f);
    Xout2[(size_t)wid * 64 + lane] = acc;
    if (pool_flag) {
        int g = batch[wid];
        atomicAdd(&pooled[g * DIM + 2 * lane], acc.x);
        atomicAdd(&pooled[g * DIM + 2 * lane + 1], acc.y);
    }
}

__global__ void final_kernel(const float* __restrict__ pooled, const float* __restrict__ Wf,
                             const float* __restrict__ bf, float* __restrict__ y) {
    int wid = (blockIdx.x * blockDim.x + threadIdx.x) >> 6;
    int lane = threadIdx.x & 63;
    if (wid >= N_GRAPHS) return;
    float2 p = *(const float2*)&pooled[wid * DIM + 2 * lane];
    float2 w = *(const float2*)&Wf[2 * lane];
    float v = p.x * w.x + p.y * w.y;
    for (int off = 32; off; off >>= 1) v += __shfl_down(v, off);
    if (lane == 0) y[wid] = v + bf[0];
}

extern "C" void kernel_launch(void* const* d_in, const int* in_sizes, int n_in,
                              void* d_out, int out_size, void* d_ws, size_t ws_size,
                              hipStream_t stream) {
    const float* x       = (const float*)d_in[0];
    const int*   ei      = (const int*)d_in[1];
    const int*   batch   = (const int*)d_in[2];
    const float* Ws      = (const float*)d_in[3];
    const float* att_src = (const float*)d_in[4];
    const float* att_dst = (const float*)d_in[5];
    const float* biases  = (const float*)d_in[6];
    const float* Wf      = (const float*)d_in[7];
    const float* bf      = (const float*)d_in[8];
    float* y = (float*)d_out;

    char* p = (char*)d_ws;
    auto alloc = [&](size_t bytes) -> void* {
        void* r = (void*)p;
        p += (bytes + 255) & ~(size_t)255;
        return r;
    };
    float* xA      = (float*)alloc((size_t)N_NODES * DIM * 4);
    float* xB      = (float*)alloc((size_t)N_NODES * DIM * 4);
    uint*  Hb      = (uint*)alloc((size_t)N_NODES * 32 * 4);   // fp8 e4m3 packed, 128 B/row
    int*   csr_src = (int*)alloc((size_t)E_CAP * 4);
    int*   deg     = (int*)alloc((size_t)N_NODES * 4);
    int*   fillc   = (int*)alloc((size_t)N_NODES * 4);
    int*   row_ptr = (int*)alloc((size_t)(N_NODES + 1) * 4);
    int*   blksum  = (int*)alloc(256 * 4);
    float* s1      = (float*)alloc((size_t)N_NODES * 4);
    float* s2      = (float*)alloc((size_t)N_NODES * 4);
    float* pooled  = (float*)alloc((size_t)N_GRAPHS * DIM * 4);

    const int BN = 256;
    const int gN   = (N_NODES + BN - 1) / BN;
    const int gE   = (E_TOT + BN - 1) / BN;
    const int gI   = (E_CAP + BN - 1) / BN;
    const int gNW  = (N_NODES * 64 + BN - 1) / BN;  // one wave per node
    const int nblk = gN;

    init_kernel<<<gI, BN, 0, stream>>>(deg, fillc, pooled, csr_src);
    count_kernel<<<gE, BN, 0, stream>>>(ei, deg);
    scan1_kernel<<<nblk, BN, 0, stream>>>(deg, row_ptr, blksum, N_NODES);
    scan2_kernel<<<1, BN, 0, stream>>>(blksum, row_ptr, nblk);
    scan3_kernel<<<gN, BN, 0, stream>>>(row_ptr, blksum, N_NODES);
    fill_kernel<<<gE, BN, 0, stream>>>(ei, row_ptr, fillc, csr_src);

    const float* xin = x;
    float* xout = xA;
    for (int l = 0; l < 3; ++l) {
        const float* W  = Ws + (size_t)l * DIM * DIM;
        const float* as = att_src + (size_t)l * DIM;
        const float* ad = att_dst + (size_t)l * DIM;
        const float* b  = biases + (size_t)l * DIM;

        gemm_dots_kernel<<<(N_NODES + 127) / 128, BN, 0, stream>>>(xin, W, as, ad, Hb, s1, s2, N_NODES);
        agg_kernel<<<gNW, BN, 0, stream>>>((const ushort*)Hb, csr_src, row_ptr, s1, s2, b,
                                           (float2*)xout, batch, pooled,
                                           (l == 2) ? 1 : 0, N_NODES);
        xin = xout;
        xout = (l == 0) ? xB : xA;
    }

    final_kernel<<<(N_GRAPHS * 64 + BN - 1) / BN, BN, 0, stream>>>(pooled, Wf, bf, y);
    (void)ws_size; (void)n_in; (void)in_sizes; (void)out_size;
}